// Round 1
// baseline (133860.071 us; speedup 1.0000x reference)
//
#include <hip/hip_runtime.h>
#include <hip/hip_cooperative_groups.h>

namespace cg = cooperative_groups;

#define M_ROWS 2048
#define N_COLS 4096
#define RHO_C 1.0f
#define STEP_C 5e-05f
#define MAX_ITERS_C 100
#define INNER_C 20

// One persistent cooperative kernel: 256 blocks (1 per CU) x 1024 threads.
// Block b owns rows [8b, 8b+8) of A (for A@x) and cols [16b, 16b+16) (for A^T t).
// A (32 MiB fp32) stays L2/L3-resident; per-step per-CU traffic = 256 KiB.

__global__ __launch_bounds__(1024) void admm_persistent(
    const float* __restrict__ A, const float* __restrict__ bvec,
    const float* __restrict__ cvec, float* __restrict__ out,
    float* __restrict__ x, float* __restrict__ t, float* __restrict__ Ax,
    float* __restrict__ s, float* __restrict__ u, float* __restrict__ rt)
{
    cg::grid_group grid = cg::this_grid();
    const int tid  = threadIdx.x;
    const int blk  = blockIdx.x;
    const int lane = tid & 63;
    const int wave = tid >> 6;

    __shared__ float  xl[N_COLS];   // 16 KiB staged x
    __shared__ float  tl[M_ROWS];   //  8 KiB staged t
    __shared__ float4 gred[64];     //  1 KiB partials for column reduce

    // ---- init (ws is poisoned 0xAA before every launch) ----
    {
        int gi = blk * 1024 + tid;
        if (gi < N_COLS) x[gi] = 0.0f;
        if (gi < M_ROWS) { s[gi] = 0.0f; u[gi] = 0.0f; rt[gi] = bvec[gi]; }
    }
    grid.sync();

    const float4* A4 = reinterpret_cast<const float4*>(A);

    for (int outer = 0; outer < MAX_ITERS_C; ++outer) {
        // ---- inner PGD loop ----
        for (int inner = 0; inner < INNER_C; ++inner) {
            // stage x -> LDS (1024 threads x float4 = 4096 floats)
            reinterpret_cast<float4*>(xl)[tid] =
                reinterpret_cast<const float4*>(x)[tid];
            __syncthreads();

            // t-phase: t[i] = A[i,:].x - rt[i], waves 0..7, one row each
            if (wave < 8) {
                const int i = blk * 8 + wave;
                const float4* Ar  = A4 + (size_t)i * (N_COLS / 4);
                const float4* xl4 = reinterpret_cast<const float4*>(xl);
                float4 acc = {0.f, 0.f, 0.f, 0.f};
                #pragma unroll
                for (int it = 0; it < 16; ++it) {
                    float4 a  = Ar[it * 64 + lane];
                    float4 xv = xl4[it * 64 + lane];
                    acc.x += a.x * xv.x; acc.y += a.y * xv.y;
                    acc.z += a.z * xv.z; acc.w += a.w * xv.w;
                }
                float d = acc.x + acc.y + acc.z + acc.w;
                #pragma unroll
                for (int off = 32; off > 0; off >>= 1) d += __shfl_xor(d, off);
                if (lane == 0) t[i] = d - rt[i];
            }
            grid.sync();

            // g-phase: for block's 16 cols j: g = c[j] + rho * sum_i A[i][j]*t[i]
            // stage t -> LDS
            reinterpret_cast<float2*>(tl)[tid] =
                reinterpret_cast<const float2*>(t)[tid];
            __syncthreads();
            {
                const int p  = tid >> 2;   // 0..255  (row partial index)
                const int gq = tid & 3;    // 0..3    (column quad)
                float4 acc = {0.f, 0.f, 0.f, 0.f};
                #pragma unroll
                for (int k = 0; k < 8; ++k) {
                    const int i = p + 256 * k;
                    const float tv = tl[i];
                    float4 a = A4[(size_t)i * (N_COLS / 4) + (blk * 16) / 4 + gq];
                    acc.x += a.x * tv; acc.y += a.y * tv;
                    acc.z += a.z * tv; acc.w += a.w * tv;
                }
                // in-wave reduce over p_local (lane = p_local*4 + gq)
                #pragma unroll
                for (int off = 4; off < 64; off <<= 1) {
                    acc.x += __shfl_xor(acc.x, off);
                    acc.y += __shfl_xor(acc.y, off);
                    acc.z += __shfl_xor(acc.z, off);
                    acc.w += __shfl_xor(acc.w, off);
                }
                if ((lane >> 2) == 0) gred[wave * 4 + gq] = acc;
            }
            __syncthreads();
            if (tid < 4) {
                float4 tot = {0.f, 0.f, 0.f, 0.f};
                #pragma unroll
                for (int w = 0; w < 16; ++w) {
                    float4 v = gred[w * 4 + tid];
                    tot.x += v.x; tot.y += v.y; tot.z += v.z; tot.w += v.w;
                }
                const int jb = blk * 16 + tid * 4;
                float tt[4] = {tot.x, tot.y, tot.z, tot.w};
                #pragma unroll
                for (int e = 0; e < 4; ++e) {
                    const int j = jb + e;
                    float gj = cvec[j] + RHO_C * tt[e];
                    float xn = x[j] - STEP_C * gj;
                    x[j] = xn > 0.f ? xn : 0.f;
                }
            }
            grid.sync();
        }

        // ---- Ax with final x ----
        reinterpret_cast<float4*>(xl)[tid] =
            reinterpret_cast<const float4*>(x)[tid];
        __syncthreads();
        if (wave < 8) {
            const int i = blk * 8 + wave;
            const float4* Ar  = A4 + (size_t)i * (N_COLS / 4);
            const float4* xl4 = reinterpret_cast<const float4*>(xl);
            float4 acc = {0.f, 0.f, 0.f, 0.f};
            #pragma unroll
            for (int it = 0; it < 16; ++it) {
                float4 a  = Ar[it * 64 + lane];
                float4 xv = xl4[it * 64 + lane];
                acc.x += a.x * xv.x; acc.y += a.y * xv.y;
                acc.z += a.z * xv.z; acc.w += a.w * xv.w;
            }
            float d = acc.x + acc.y + acc.z + acc.w;
            #pragma unroll
            for (int off = 32; off > 0; off >>= 1) d += __shfl_xor(d, off);
            if (lane == 0) Ax[i] = d;
        }
        grid.sync();

        // ---- s, u, rt elementwise update ----
        {
            const int gi = blk * 1024 + tid;
            if (gi < M_ROWS) {
                const float a  = Ax[gi];
                const float bb = bvec[gi];
                const float uu = u[gi];
                float sn = a - bb + uu; sn = sn > 0.f ? sn : 0.f;
                const float un = uu + a - sn - bb;
                s[gi]  = sn;
                u[gi]  = un;
                rt[gi] = sn + bb - un;
            }
        }
        grid.sync();
    }

    // ---- outputs: [x(4096), s(2048), u(2048), -u(2048)] ----
    {
        const int gi = blk * 1024 + tid;
        if (gi < N_COLS) out[gi] = x[gi];
        if (gi < M_ROWS) {
            out[4096 + gi] = s[gi];
            out[6144 + gi] = u[gi];
            out[8192 + gi] = -u[gi];
        }
    }
}

extern "C" void kernel_launch(void* const* d_in, const int* in_sizes, int n_in,
                              void* d_out, int out_size, void* d_ws, size_t ws_size,
                              hipStream_t stream) {
    const float* A    = (const float*)d_in[0];   // 2048*4096
    const float* bvec = (const float*)d_in[1];   // 2048
    const float* cvec = (const float*)d_in[2];   // 4096
    float* out = (float*)d_out;

    float* ws = (float*)d_ws;
    float* x  = ws;              // 4096
    float* t  = x  + N_COLS;     // 2048
    float* Ax = t  + M_ROWS;     // 2048
    float* s  = Ax + M_ROWS;     // 2048
    float* u  = s  + M_ROWS;     // 2048
    float* rt = u  + M_ROWS;     // 2048

    void* args[] = { (void*)&A, (void*)&bvec, (void*)&cvec, (void*)&out,
                     (void*)&x, (void*)&t, (void*)&Ax, (void*)&s, (void*)&u,
                     (void*)&rt };
    hipLaunchCooperativeKernel((const void*)admm_persistent,
                               dim3(256), dim3(1024), args, 0, stream);
}

// Round 3
// 31981.131 us; speedup vs baseline: 4.1856x; 4.1856x over previous
//
#include <hip/hip_runtime.h>
#include <hip/hip_cooperative_groups.h>

namespace cg = cooperative_groups;

#define M_ROWS 2048
#define N_COLS 4096
#define RHO_C 1.0f
#define STEP_C 5e-05f
#define MAX_ITERS_C 100
#define INNER_C 20

// Fast 2-level grid barrier. Monotonic counters (no resets, no sense flag).
// bs layout (uint): leaf[g] at bs[g*32] (g<8, 128B apart), root at bs[256],
// epoch at bs[288]. Rep thread = tid 0 (block = 1 CU => one L1, so rep's
// acquire fence (buffer_inv) covers the whole block's L1).
__device__ inline void fast_barrier(unsigned* bs, int blk, unsigned n) {
    __syncthreads();
    if (threadIdx.x == 0) {
        __builtin_amdgcn_fence(__ATOMIC_RELEASE, "agent");
        unsigned* leaf = bs + ((blk & 7) << 5);
        unsigned* root = bs + 256;
        unsigned* ep   = bs + 288;
        unsigned old = __hip_atomic_fetch_add(leaf, 1u, __ATOMIC_RELAXED,
                                              __HIP_MEMORY_SCOPE_AGENT);
        if (old == n * 32u + 31u) {          // last arrival in this leaf
            unsigned ro = __hip_atomic_fetch_add(root, 1u, __ATOMIC_RELAXED,
                                                 __HIP_MEMORY_SCOPE_AGENT);
            if (ro == n * 8u + 7u) {         // last leaf -> publish epoch n+1
                __hip_atomic_fetch_add(ep, 1u, __ATOMIC_RELEASE,
                                       __HIP_MEMORY_SCOPE_AGENT);
            }
        }
        while (__hip_atomic_load(ep, __ATOMIC_RELAXED,
                                 __HIP_MEMORY_SCOPE_AGENT) <= n) { }
        __builtin_amdgcn_fence(__ATOMIC_ACQUIRE, "agent");
    }
    __syncthreads();
}

// 256 blocks (1/CU) x 1024 threads, persistent cooperative kernel.
// Block b owns rows [8b,8b+8) (A@x) and cols [16b,16b+16) (A^T t).
__global__ __launch_bounds__(1024) void admm_persistent(
    const float* __restrict__ A, const float* __restrict__ bvec,
    const float* __restrict__ cvec, float* __restrict__ out,
    float* __restrict__ x, float* __restrict__ t, float* __restrict__ Ax,
    float* __restrict__ s, float* __restrict__ u, float* __restrict__ rt,
    unsigned* __restrict__ bstate)
{
    cg::grid_group grid = cg::this_grid();
    const int tid  = threadIdx.x;
    const int blk  = blockIdx.x;
    const int lane = tid & 63;
    const int wave = tid >> 6;

    __shared__ float  xl[N_COLS];   // 16 KiB staged x
    __shared__ float  tl[M_ROWS];   //  8 KiB staged t
    __shared__ float4 gred[64];     //  1 KiB partials for column reduce
    __shared__ float  tpart[16];    //  row half-dot partials

    // ---- init (ws poisoned 0xAA before every launch) ----
    {
        int gi = blk * 1024 + tid;
        if (gi < N_COLS) x[gi] = 0.0f;
        if (gi < M_ROWS) { s[gi] = 0.0f; u[gi] = 0.0f; rt[gi] = bvec[gi]; }
        if (blk == 0 && tid < 320) bstate[tid] = 0u;
    }
    grid.sync();               // cg sync ONCE (to publish zeroed bstate)
    unsigned bar_n = 0;

    const float4* A4 = reinterpret_cast<const float4*>(A);

    for (int outer = 0; outer < MAX_ITERS_C; ++outer) {
        for (int inner = 0; inner < INNER_C; ++inner) {
            // stage x -> LDS
            reinterpret_cast<float4*>(xl)[tid] =
                reinterpret_cast<const float4*>(x)[tid];
            __syncthreads();

            // t-phase: 16 waves, wave w = row (w>>1), half (w&1)
            {
                const int r = blk * 8 + (wave >> 1);
                const int h = wave & 1;
                const float4* Ar  = A4 + (size_t)r * (N_COLS / 4) + h * 512;
                const float4* xh  = reinterpret_cast<const float4*>(xl) + h * 512;
                float4 acc = {0.f, 0.f, 0.f, 0.f};
                #pragma unroll
                for (int it = 0; it < 8; ++it) {
                    float4 a  = Ar[it * 64 + lane];
                    float4 xv = xh[it * 64 + lane];
                    acc.x += a.x * xv.x; acc.y += a.y * xv.y;
                    acc.z += a.z * xv.z; acc.w += a.w * xv.w;
                }
                float d = acc.x + acc.y + acc.z + acc.w;
                #pragma unroll
                for (int off = 32; off > 0; off >>= 1) d += __shfl_xor(d, off);
                if (lane == 0) tpart[wave] = d;
            }
            __syncthreads();
            if (tid < 8) {
                const int i = blk * 8 + tid;
                t[i] = tpart[2 * tid] + tpart[2 * tid + 1] - rt[i];
            }
            fast_barrier(bstate, blk, bar_n); ++bar_n;

            // g-phase: cols [16b,16b+16): g = c + rho * A(:,j)^T t
            reinterpret_cast<float2*>(tl)[tid] =
                reinterpret_cast<const float2*>(t)[tid];
            __syncthreads();
            {
                const int p  = tid >> 2;   // 0..255 row partial index
                const int gq = tid & 3;    // col quad
                float4 acc = {0.f, 0.f, 0.f, 0.f};
                #pragma unroll
                for (int k = 0; k < 8; ++k) {
                    const int i = p + 256 * k;
                    const float tv = tl[i];
                    float4 a = A4[(size_t)i * (N_COLS / 4) + blk * 4 + gq];
                    acc.x += a.x * tv; acc.y += a.y * tv;
                    acc.z += a.z * tv; acc.w += a.w * tv;
                }
                #pragma unroll
                for (int off = 4; off < 64; off <<= 1) {
                    acc.x += __shfl_xor(acc.x, off);
                    acc.y += __shfl_xor(acc.y, off);
                    acc.z += __shfl_xor(acc.z, off);
                    acc.w += __shfl_xor(acc.w, off);
                }
                if ((lane >> 2) == 0) gred[wave * 4 + gq] = acc;
            }
            __syncthreads();
            if (tid < 4) {
                float4 tot = {0.f, 0.f, 0.f, 0.f};
                #pragma unroll
                for (int w = 0; w < 16; ++w) {
                    float4 v = gred[w * 4 + tid];
                    tot.x += v.x; tot.y += v.y; tot.z += v.z; tot.w += v.w;
                }
                const int jb = blk * 16 + tid * 4;
                float tt[4] = {tot.x, tot.y, tot.z, tot.w};
                #pragma unroll
                for (int e = 0; e < 4; ++e) {
                    const int j = jb + e;
                    float gj = cvec[j] + RHO_C * tt[e];
                    float xn = xl[j] - STEP_C * gj;
                    x[j] = xn > 0.f ? xn : 0.f;
                }
            }
            fast_barrier(bstate, blk, bar_n); ++bar_n;
        }

        // ---- Ax with final x (16 waves, half-rows) ----
        reinterpret_cast<float4*>(xl)[tid] =
            reinterpret_cast<const float4*>(x)[tid];
        __syncthreads();
        {
            const int r = blk * 8 + (wave >> 1);
            const int h = wave & 1;
            const float4* Ar  = A4 + (size_t)r * (N_COLS / 4) + h * 512;
            const float4* xh  = reinterpret_cast<const float4*>(xl) + h * 512;
            float4 acc = {0.f, 0.f, 0.f, 0.f};
            #pragma unroll
            for (int it = 0; it < 8; ++it) {
                float4 a  = Ar[it * 64 + lane];
                float4 xv = xh[it * 64 + lane];
                acc.x += a.x * xv.x; acc.y += a.y * xv.y;
                acc.z += a.z * xv.z; acc.w += a.w * xv.w;
            }
            float d = acc.x + acc.y + acc.z + acc.w;
            #pragma unroll
            for (int off = 32; off > 0; off >>= 1) d += __shfl_xor(d, off);
            if (lane == 0) tpart[wave] = d;
        }
        __syncthreads();
        if (tid < 8) Ax[blk * 8 + tid] = tpart[2 * tid] + tpart[2 * tid + 1];
        fast_barrier(bstate, blk, bar_n); ++bar_n;

        // ---- s, u, rt elementwise ----
        {
            const int gi = blk * 1024 + tid;
            if (gi < M_ROWS) {
                const float a  = Ax[gi];
                const float bb = bvec[gi];
                const float uu = u[gi];
                float sn = a - bb + uu; sn = sn > 0.f ? sn : 0.f;
                const float un = uu + a - sn - bb;
                s[gi]  = sn;
                u[gi]  = un;
                rt[gi] = sn + bb - un;
            }
        }
        fast_barrier(bstate, blk, bar_n); ++bar_n;
    }

    // ---- outputs: [x(4096), s(2048), u(2048), -u(2048)] ----
    {
        const int gi = blk * 1024 + tid;
        if (gi < N_COLS) out[gi] = x[gi];
        if (gi < M_ROWS) {
            out[4096 + gi] = s[gi];
            out[6144 + gi] = u[gi];
            out[8192 + gi] = -u[gi];
        }
    }
}

extern "C" void kernel_launch(void* const* d_in, const int* in_sizes, int n_in,
                              void* d_out, int out_size, void* d_ws, size_t ws_size,
                              hipStream_t stream) {
    const float* A    = (const float*)d_in[0];   // 2048*4096
    const float* bvec = (const float*)d_in[1];   // 2048
    const float* cvec = (const float*)d_in[2];   // 4096
    float* out = (float*)d_out;

    float* ws = (float*)d_ws;
    float* x  = ws;              // 4096
    float* t  = x  + N_COLS;     // 2048
    float* Ax = t  + M_ROWS;     // 2048
    float* s  = Ax + M_ROWS;     // 2048
    float* u  = s  + M_ROWS;     // 2048
    float* rt = u  + M_ROWS;     // 2048
    // barrier state: 128B-aligned region well past the vectors
    unsigned* bstate = (unsigned*)(ws + 32768);  // at 128 KiB offset, 320 uints

    void* args[] = { (void*)&A, (void*)&bvec, (void*)&cvec, (void*)&out,
                     (void*)&x, (void*)&t, (void*)&Ax, (void*)&s, (void*)&u,
                     (void*)&rt, (void*)&bstate };
    hipError_t err = hipLaunchCooperativeKernel((const void*)admm_persistent,
                               dim3(256), dim3(1024), args, 0, stream);
    (void)err;
}

// Round 4
// 10898.896 us; speedup vs baseline: 12.2820x; 2.9343x over previous
//
#include <hip/hip_runtime.h>
#include <hip/hip_cooperative_groups.h>

namespace cg = cooperative_groups;

#define M_ROWS 2048
#define N_COLS 4096
#define RHO_C 1.0f
#define STEP_C 5e-05f
#define MAX_ITERS_C 100
#define INNER_C 20

// Relaxed agent-scope atomics: coherent at the Infinity Cache (sc1 path),
// bypassing per-XCD L2 / per-CU L1 — so no fences with cache ops are needed.
__device__ __forceinline__ float aload(const float* p) {
    return __hip_atomic_load(p, __ATOMIC_RELAXED, __HIP_MEMORY_SCOPE_AGENT);
}
__device__ __forceinline__ void astore(float* p, float v) {
    __hip_atomic_store(p, v, __ATOMIC_RELAXED, __HIP_MEMORY_SCOPE_AGENT);
}

// Fence-light 2-level grid barrier. Monotonic counters, no resets.
// Leaves: bs[g*32], g<8 (128 B apart). Root: bs[256]. Epoch: bs[288].
// Only workgroup fences (s_waitcnt, no buffer_inv/wbl2) — cross-block data
// is published/consumed via sc1 atomics, which are IC-coherent by construction.
__device__ inline void fast_barrier(unsigned* bs, int blk, unsigned n) {
    __syncthreads();   // each wave drains its own vmcnt before s_barrier
    if (threadIdx.x == 0) {
        __builtin_amdgcn_fence(__ATOMIC_RELEASE, "workgroup");
        unsigned* leaf = bs + ((blk & 7) << 5);
        unsigned* root = bs + 256;
        unsigned* ep   = bs + 288;
        unsigned old = __hip_atomic_fetch_add(leaf, 1u, __ATOMIC_RELAXED,
                                              __HIP_MEMORY_SCOPE_AGENT);
        if (old == n * 32u + 31u) {
            unsigned ro = __hip_atomic_fetch_add(root, 1u, __ATOMIC_RELAXED,
                                                 __HIP_MEMORY_SCOPE_AGENT);
            if (ro == n * 8u + 7u)
                __hip_atomic_fetch_add(ep, 1u, __ATOMIC_RELAXED,
                                       __HIP_MEMORY_SCOPE_AGENT);
        }
        while (__hip_atomic_load(ep, __ATOMIC_RELAXED,
                                 __HIP_MEMORY_SCOPE_AGENT) <= n)
            __builtin_amdgcn_s_sleep(1);
        __builtin_amdgcn_fence(__ATOMIC_ACQUIRE, "workgroup");
    }
    __syncthreads();
}

// 256 blocks (1/CU) x 1024 threads (16 waves), persistent cooperative kernel.
// Gram form: g = c + rho*(M x - A^T rt), M = A^T A held ENTIRELY in registers:
// thread (wave w, lane l): accM[r][k] = M[16*blk + 4*(w&3)+r][1024*(w>>2)+l+64k]
// Block b also owns rows [8b,8b+8) of A (Ax / s,u,rt) and x entries [16b,16b+16).
__global__ __launch_bounds__(1024) void admm_gram(
    const float* __restrict__ A, const float* __restrict__ bvec,
    const float* __restrict__ cvec, float* __restrict__ out,
    float* __restrict__ x0, float* __restrict__ x1,
    float* __restrict__ rt, unsigned* __restrict__ bstate)
{
    cg::grid_group grid = cg::this_grid();
    const int tid  = threadIdx.x;
    const int blk  = blockIdx.x;
    const int lane = tid & 63;
    const int wave = tid >> 6;
    const int cgp  = wave >> 2;   // col-group: cols [1024*cgp, +1024)
    const int rq   = wave & 3;    // row-quad : rows 16*blk + 4*rq .. +4

    __shared__ float  abuf[4 * N_COLS];  // 64 KB staging (A rows / x / rt)
    __shared__ float  red[4][16];        // per-colgroup row partials
    __shared__ float4 gred[64];          // w-phase reduce scratch
    __shared__ float  xown[16], wl[16], cw[16];
    __shared__ float  sv[8], uv[8], tpart[16];

    const float4* A4 = reinterpret_cast<const float4*>(A);
    float4* abuf4 = reinterpret_cast<float4*>(abuf);

    // ---- init ----
    if (tid < 16) {
        cw[tid] = cvec[blk * 16 + tid];
        astore(&x0[blk * 16 + tid], 0.0f);
    }
    if (tid < 8) {
        sv[tid] = 0.0f; uv[tid] = 0.0f;
        astore(&rt[blk * 8 + tid], bvec[blk * 8 + tid]);
    }
    if (blk == 0 && tid < 320) bstate[tid] = 0u;

    // ---- precompute register-resident M fragment ----
    float accM[4][16];
    #pragma unroll
    for (int r = 0; r < 4; ++r)
        #pragma unroll
        for (int k = 0; k < 16; ++k) accM[r][k] = 0.0f;

    for (int i0 = 0; i0 < M_ROWS; i0 += 4) {
        #pragma unroll
        for (int ii = 0; ii < 4; ++ii)
            abuf4[ii * 1024 + tid] = A4[(size_t)(i0 + ii) * 1024 + tid];
        __syncthreads();
        #pragma unroll
        for (int ii = 0; ii < 4; ++ii) {
            const float* row = abuf + ii * N_COLS;
            float av[16];
            #pragma unroll
            for (int k = 0; k < 16; ++k) av[k] = row[cgp * 1024 + lane + 64 * k];
            float cb[4];
            #pragma unroll
            for (int r = 0; r < 4; ++r) cb[r] = row[blk * 16 + rq * 4 + r];
            #pragma unroll
            for (int r = 0; r < 4; ++r)
                #pragma unroll
                for (int k = 0; k < 16; ++k)
                    accM[r][k] = fmaf(cb[r], av[k], accM[r][k]);
        }
        __syncthreads();
    }

    grid.sync();   // single cg sync: publishes x0/rt/bstate
    unsigned bar_n = 0;

    for (int outer = 0; outer < MAX_ITERS_C; ++outer) {
        // ---- w-phase (block-local result): wl = (A^T rt)[16b..16b+16) ----
        abuf[tid]        = aload(&rt[tid]);
        abuf[tid + 1024] = aload(&rt[tid + 1024]);
        __syncthreads();
        {
            const int p = tid >> 2, gq = tid & 3;
            float4 acc = {0.f, 0.f, 0.f, 0.f};
            #pragma unroll
            for (int k2 = 0; k2 < 8; ++k2) {
                const int i = p + 256 * k2;
                const float tv = abuf[i];
                float4 a = A4[(size_t)i * 1024 + blk * 4 + gq];
                acc.x = fmaf(a.x, tv, acc.x); acc.y = fmaf(a.y, tv, acc.y);
                acc.z = fmaf(a.z, tv, acc.z); acc.w = fmaf(a.w, tv, acc.w);
            }
            #pragma unroll
            for (int off = 4; off < 64; off <<= 1) {
                acc.x += __shfl_xor(acc.x, off);
                acc.y += __shfl_xor(acc.y, off);
                acc.z += __shfl_xor(acc.z, off);
                acc.w += __shfl_xor(acc.w, off);
            }
            if ((lane >> 2) == 0) gred[wave * 4 + gq] = acc;
        }
        __syncthreads();
        if (tid < 4) {
            float4 tot = {0.f, 0.f, 0.f, 0.f};
            #pragma unroll
            for (int w = 0; w < 16; ++w) {
                float4 v = gred[w * 4 + tid];
                tot.x += v.x; tot.y += v.y; tot.z += v.z; tot.w += v.w;
            }
            wl[tid * 4 + 0] = tot.x; wl[tid * 4 + 1] = tot.y;
            wl[tid * 4 + 2] = tot.z; wl[tid * 4 + 3] = tot.w;
        }
        __syncthreads();

        // ---- inner PGD: x <- relu(x - step*(c + rho*(Mx - wl))) ----
        for (int inner = 0; inner < INNER_C; ++inner) {
            const float* xsrc = (inner & 1) ? x1 : x0;
            float*       xdst = (inner & 1) ? x0 : x1;

            float xr[16];
            #pragma unroll
            for (int k = 0; k < 16; ++k)
                xr[k] = aload(&xsrc[cgp * 1024 + lane + 64 * k]);

            float pdot[4];
            #pragma unroll
            for (int r = 0; r < 4; ++r) {
                float pp = 0.f;
                #pragma unroll
                for (int k = 0; k < 16; ++k)
                    pp = fmaf(accM[r][k], xr[k], pp);
                pdot[r] = pp;
            }

            // publish this block's own x_old entries to the updater threads
            // j = 16b+t: colgroup blk>>6, lane 16(blk&3)+t, reg (blk>>2)&15
            {
                const int ksel = (blk >> 2) & 15;
                float xv = 0.f;
                #pragma unroll
                for (int k = 0; k < 16; ++k) xv = (k == ksel) ? xr[k] : xv;
                if (cgp == (blk >> 6) && rq == 0 && (lane >> 4) == (blk & 3))
                    xown[lane & 15] = xv;
            }

            #pragma unroll
            for (int r = 0; r < 4; ++r) {
                float v = pdot[r];
                #pragma unroll
                for (int off = 32; off; off >>= 1) v += __shfl_xor(v, off);
                if (lane == 0) red[cgp][rq * 4 + r] = v;
            }
            __syncthreads();

            if (tid < 16) {
                const float y = red[0][tid] + red[1][tid]
                              + red[2][tid] + red[3][tid];
                const float g = cw[tid] + RHO_C * (y - wl[tid]);
                float xn = xown[tid] - STEP_C * g;
                xn = xn > 0.f ? xn : 0.f;
                astore(&xdst[blk * 16 + tid], xn);
            }
            fast_barrier(bstate, blk, bar_n); ++bar_n;
        }
        // INNER_C even -> final x is in x0

        // ---- Ax on own 8 rows + s,u,rt update (block-local) ----
        #pragma unroll
        for (int k = 0; k < 4; ++k)
            abuf[tid + 1024 * k] = aload(&x0[tid + 1024 * k]);
        __syncthreads();
        {
            const int r = blk * 8 + (wave >> 1), h = wave & 1;
            const float4* Ar = A4 + (size_t)r * 1024 + h * 512;
            const float4* xh = reinterpret_cast<const float4*>(abuf) + h * 512;
            float4 acc = {0.f, 0.f, 0.f, 0.f};
            #pragma unroll
            for (int it = 0; it < 8; ++it) {
                float4 a = Ar[it * 64 + lane], xv = xh[it * 64 + lane];
                acc.x = fmaf(a.x, xv.x, acc.x); acc.y = fmaf(a.y, xv.y, acc.y);
                acc.z = fmaf(a.z, xv.z, acc.z); acc.w = fmaf(a.w, xv.w, acc.w);
            }
            float d = acc.x + acc.y + acc.z + acc.w;
            #pragma unroll
            for (int off = 32; off; off >>= 1) d += __shfl_xor(d, off);
            if (lane == 0) tpart[wave] = d;
        }
        __syncthreads();
        if (tid < 8) {
            const int i = blk * 8 + tid;
            const float a  = tpart[2 * tid] + tpart[2 * tid + 1];
            const float bb = bvec[i];
            const float uu = uv[tid];
            float sn = a - bb + uu; sn = sn > 0.f ? sn : 0.f;
            const float un = uu + a - sn - bb;
            sv[tid] = sn; uv[tid] = un;
            astore(&rt[i], sn + bb - un);
        }
        fast_barrier(bstate, blk, bar_n); ++bar_n;
    }

    // ---- outputs: [x(4096), s(2048), u(2048), -u(2048)] ----
    if (tid < 16) out[blk * 16 + tid] = aload(&x0[blk * 16 + tid]);
    if (tid < 8) {
        const int i = blk * 8 + tid;
        out[4096 + i] = sv[tid];
        out[6144 + i] = uv[tid];
        out[8192 + i] = -uv[tid];
    }
}

extern "C" void kernel_launch(void* const* d_in, const int* in_sizes, int n_in,
                              void* d_out, int out_size, void* d_ws, size_t ws_size,
                              hipStream_t stream) {
    const float* A    = (const float*)d_in[0];   // 2048*4096
    const float* bvec = (const float*)d_in[1];   // 2048
    const float* cvec = (const float*)d_in[2];   // 4096
    float* out = (float*)d_out;

    float* ws = (float*)d_ws;
    float* x0 = ws;                    // 4096
    float* x1 = ws + 4096;             // 4096
    float* rt = ws + 8192;             // 2048
    unsigned* bstate = (unsigned*)(ws + 12288);  // 320 uints, 128B-spread leaves

    void* args[] = { (void*)&A, (void*)&bvec, (void*)&cvec, (void*)&out,
                     (void*)&x0, (void*)&x1, (void*)&rt, (void*)&bstate };
    hipError_t err = hipLaunchCooperativeKernel((const void*)admm_gram,
                               dim3(256), dim3(1024), args, 0, stream);
    (void)err;
}

// Round 5
// 10822.265 us; speedup vs baseline: 12.3690x; 1.0071x over previous
//
#include <hip/hip_runtime.h>
#include <hip/hip_cooperative_groups.h>

namespace cg = cooperative_groups;

#define M_ROWS 2048
#define N_COLS 4096
#define RHO_C 1.0f
#define STEP_C 5e-05f
#define MAX_ITERS_C 100
#define INNER_C 20

// Relaxed agent-scope atomics: coherent at the Infinity Cache (sc1 path),
// bypassing per-XCD L2 / per-CU L1 — no cache-op fences needed.
__device__ __forceinline__ float aload(const float* p) {
    return __hip_atomic_load(p, __ATOMIC_RELAXED, __HIP_MEMORY_SCOPE_AGENT);
}
__device__ __forceinline__ void astore(float* p, float v) {
    __hip_atomic_store(p, v, __ATOMIC_RELAXED, __HIP_MEMORY_SCOPE_AGENT);
}
__device__ __forceinline__ float2 aload2(const float* p) {
    unsigned long long v = __hip_atomic_load(
        (const unsigned long long*)p, __ATOMIC_RELAXED,
        __HIP_MEMORY_SCOPE_AGENT);
    union { unsigned long long u; float2 f; } c; c.u = v; return c.f;
}

// Fence-light 2-level grid barrier. Monotonic counters, no resets.
// Leaves: bs[g*32], g<8 (128 B apart). Root: bs[256]. Epoch: bs[288].
__device__ inline void fast_barrier(unsigned* bs, int blk, unsigned n) {
    __syncthreads();   // each wave drains its own vmcnt before s_barrier
    if (threadIdx.x == 0) {
        __builtin_amdgcn_fence(__ATOMIC_RELEASE, "workgroup");
        unsigned* leaf = bs + ((blk & 7) << 5);
        unsigned* root = bs + 256;
        unsigned* ep   = bs + 288;
        unsigned old = __hip_atomic_fetch_add(leaf, 1u, __ATOMIC_RELAXED,
                                              __HIP_MEMORY_SCOPE_AGENT);
        if (old == n * 32u + 31u) {
            unsigned ro = __hip_atomic_fetch_add(root, 1u, __ATOMIC_RELAXED,
                                                 __HIP_MEMORY_SCOPE_AGENT);
            if (ro == n * 8u + 7u)
                __hip_atomic_fetch_add(ep, 1u, __ATOMIC_RELAXED,
                                       __HIP_MEMORY_SCOPE_AGENT);
        }
        while (__hip_atomic_load(ep, __ATOMIC_RELAXED,
                                 __HIP_MEMORY_SCOPE_AGENT) <= n)
            __builtin_amdgcn_s_sleep(1);
        __builtin_amdgcn_fence(__ATOMIC_ACQUIRE, "workgroup");
    }
    __syncthreads();
}

// 256 blocks (1/CU) x 1024 threads (16 waves), persistent cooperative kernel.
// Gram form: g = c + rho*(M x - A^T rt), M = A^T A held ENTIRELY in registers:
// wave w = (cgp=w>>2, rq=w&3); thread (cgp,rq,lane):
//   accM[r][4q+e] = M[16*blk + 4*rq + r][1024*cgp + 256*q + 4*lane + e]
// so each thread's 16 x-operands are 4 contiguous float4s in a 4096-float xs.
// Block b also owns rows [8b,8b+8) of A (Ax/s,u,rt) and x entries [16b,16b+16).
__global__ __launch_bounds__(1024) void admm_gram(
    const float* __restrict__ A, const float* __restrict__ bvec,
    const float* __restrict__ cvec, float* __restrict__ out,
    float* __restrict__ x0, float* __restrict__ x1,
    float* __restrict__ rt, unsigned* __restrict__ bstate)
{
    cg::grid_group grid = cg::this_grid();
    const int tid  = threadIdx.x;
    const int blk  = blockIdx.x;
    const int lane = tid & 63;
    const int wave = tid >> 6;
    const int cgp  = wave >> 2;   // col-group: cols [1024*cgp, +1024)
    const int rq   = wave & 3;    // row-quad : rows 16*blk + 4*rq .. +4

    __shared__ float  abuf[4 * N_COLS];  // 64 KB staging (A rows / rt)
    __shared__ float4 xs4[1024];         // 16 KB staged x (and Ax-phase x)
    __shared__ float  red[4][16];        // per-colgroup row partials
    __shared__ float4 gred[64];          // w-phase reduce scratch
    __shared__ float  wl[16], cw[16];
    __shared__ float  sv[8], uv[8], tpart[16];

    float* xs = reinterpret_cast<float*>(xs4);
    const float4* A4 = reinterpret_cast<const float4*>(A);
    float4* abuf4 = reinterpret_cast<float4*>(abuf);

    // ---- init ----
    if (tid < 16) {
        cw[tid] = cvec[blk * 16 + tid];
        astore(&x0[blk * 16 + tid], 0.0f);
    }
    if (tid < 8) {
        sv[tid] = 0.0f; uv[tid] = 0.0f;
        astore(&rt[blk * 8 + tid], bvec[blk * 8 + tid]);
    }
    if (blk == 0 && tid < 320) bstate[tid] = 0u;

    // ---- precompute register-resident M fragment ----
    float accM[4][16];
    #pragma unroll
    for (int r = 0; r < 4; ++r)
        #pragma unroll
        for (int k = 0; k < 16; ++k) accM[r][k] = 0.0f;

    for (int i0 = 0; i0 < M_ROWS; i0 += 4) {
        #pragma unroll
        for (int ii = 0; ii < 4; ++ii)
            abuf4[ii * 1024 + tid] = A4[(size_t)(i0 + ii) * 1024 + tid];
        __syncthreads();
        #pragma unroll
        for (int ii = 0; ii < 4; ++ii) {
            const float*  row  = abuf + ii * N_COLS;
            const float4* row4 = abuf4 + ii * 1024;
            float4 av[4];
            #pragma unroll
            for (int q = 0; q < 4; ++q)
                av[q] = row4[256 * cgp + 64 * q + lane];
            float cb[4];
            #pragma unroll
            for (int r = 0; r < 4; ++r) cb[r] = row[blk * 16 + rq * 4 + r];
            #pragma unroll
            for (int r = 0; r < 4; ++r)
                #pragma unroll
                for (int q = 0; q < 4; ++q) {
                    accM[r][4 * q + 0] = fmaf(cb[r], av[q].x, accM[r][4 * q + 0]);
                    accM[r][4 * q + 1] = fmaf(cb[r], av[q].y, accM[r][4 * q + 1]);
                    accM[r][4 * q + 2] = fmaf(cb[r], av[q].z, accM[r][4 * q + 2]);
                    accM[r][4 * q + 3] = fmaf(cb[r], av[q].w, accM[r][4 * q + 3]);
                }
        }
        __syncthreads();
    }

    grid.sync();   // single cg sync: publishes x0/rt/bstate
    unsigned bar_n = 0;

    for (int outer = 0; outer < MAX_ITERS_C; ++outer) {
        // ---- w-phase (block-local result): wl = (A^T rt)[16b..16b+16) ----
        abuf[tid]        = aload(&rt[tid]);
        abuf[tid + 1024] = aload(&rt[tid + 1024]);
        __syncthreads();
        {
            const int p = tid >> 2, gq = tid & 3;
            float4 acc = {0.f, 0.f, 0.f, 0.f};
            #pragma unroll
            for (int k2 = 0; k2 < 8; ++k2) {
                const int i = p + 256 * k2;
                const float tv = abuf[i];
                float4 a = A4[(size_t)i * 1024 + blk * 4 + gq];
                acc.x = fmaf(a.x, tv, acc.x); acc.y = fmaf(a.y, tv, acc.y);
                acc.z = fmaf(a.z, tv, acc.z); acc.w = fmaf(a.w, tv, acc.w);
            }
            #pragma unroll
            for (int off = 4; off < 64; off <<= 1) {
                acc.x += __shfl_xor(acc.x, off);
                acc.y += __shfl_xor(acc.y, off);
                acc.z += __shfl_xor(acc.z, off);
                acc.w += __shfl_xor(acc.w, off);
            }
            if ((lane >> 2) == 0) gred[wave * 4 + gq] = acc;
        }
        __syncthreads();
        if (tid < 4) {
            float4 tot = {0.f, 0.f, 0.f, 0.f};
            #pragma unroll
            for (int w = 0; w < 16; ++w) {
                float4 v = gred[w * 4 + tid];
                tot.x += v.x; tot.y += v.y; tot.z += v.z; tot.w += v.w;
            }
            wl[tid * 4 + 0] = tot.x; wl[tid * 4 + 1] = tot.y;
            wl[tid * 4 + 2] = tot.z; wl[tid * 4 + 3] = tot.w;
        }
        __syncthreads();

        // ---- inner PGD: x <- relu(x - step*(c + rho*(Mx - wl))) ----
        for (int inner = 0; inner < INNER_C; ++inner) {
            const float* xsrc = (inner & 1) ? x1 : x0;
            float*       xdst = (inner & 1) ? x0 : x1;

            // coherent vectorized x-exchange: 16 B per thread, once
            {
                float2 lo = aload2(xsrc + 4 * tid);
                float2 hi = aload2(xsrc + 4 * tid + 2);
                xs4[tid] = make_float4(lo.x, lo.y, hi.x, hi.y);
            }
            __syncthreads();

            float4 xq[4];
            #pragma unroll
            for (int q = 0; q < 4; ++q)
                xq[q] = xs4[256 * cgp + 64 * q + lane];

            float4 pd = {0.f, 0.f, 0.f, 0.f};
            #pragma unroll
            for (int q = 0; q < 4; ++q) {
                pd.x = fmaf(accM[0][4*q+0], xq[q].x, pd.x);
                pd.x = fmaf(accM[0][4*q+1], xq[q].y, pd.x);
                pd.x = fmaf(accM[0][4*q+2], xq[q].z, pd.x);
                pd.x = fmaf(accM[0][4*q+3], xq[q].w, pd.x);
                pd.y = fmaf(accM[1][4*q+0], xq[q].x, pd.y);
                pd.y = fmaf(accM[1][4*q+1], xq[q].y, pd.y);
                pd.y = fmaf(accM[1][4*q+2], xq[q].z, pd.y);
                pd.y = fmaf(accM[1][4*q+3], xq[q].w, pd.y);
                pd.z = fmaf(accM[2][4*q+0], xq[q].x, pd.z);
                pd.z = fmaf(accM[2][4*q+1], xq[q].y, pd.z);
                pd.z = fmaf(accM[2][4*q+2], xq[q].z, pd.z);
                pd.z = fmaf(accM[2][4*q+3], xq[q].w, pd.z);
                pd.w = fmaf(accM[3][4*q+0], xq[q].x, pd.w);
                pd.w = fmaf(accM[3][4*q+1], xq[q].y, pd.w);
                pd.w = fmaf(accM[3][4*q+2], xq[q].z, pd.w);
                pd.w = fmaf(accM[3][4*q+3], xq[q].w, pd.w);
            }

            #pragma unroll
            for (int off = 32; off; off >>= 1) {
                pd.x += __shfl_xor(pd.x, off);
                pd.y += __shfl_xor(pd.y, off);
                pd.z += __shfl_xor(pd.z, off);
                pd.w += __shfl_xor(pd.w, off);
            }
            if (lane == 0) {
                red[cgp][rq * 4 + 0] = pd.x;
                red[cgp][rq * 4 + 1] = pd.y;
                red[cgp][rq * 4 + 2] = pd.z;
                red[cgp][rq * 4 + 3] = pd.w;
            }
            __syncthreads();

            if (tid < 16) {
                const float y = red[0][tid] + red[1][tid]
                              + red[2][tid] + red[3][tid];
                const float g = cw[tid] + RHO_C * (y - wl[tid]);
                float xn = xs[blk * 16 + tid] - STEP_C * g;
                xn = xn > 0.f ? xn : 0.f;
                astore(&xdst[blk * 16 + tid], xn);
            }
            fast_barrier(bstate, blk, bar_n); ++bar_n;
        }
        // INNER_C even -> final x is in x0

        // ---- Ax on own 8 rows + s,u,rt update (block-local) ----
        {
            float2 lo = aload2(x0 + 4 * tid);
            float2 hi = aload2(x0 + 4 * tid + 2);
            xs4[tid] = make_float4(lo.x, lo.y, hi.x, hi.y);
        }
        __syncthreads();
        {
            const int r = blk * 8 + (wave >> 1), h = wave & 1;
            const float4* Ar = A4 + (size_t)r * 1024 + h * 512;
            const float4* xh = xs4 + h * 512;
            float4 acc = {0.f, 0.f, 0.f, 0.f};
            #pragma unroll
            for (int it = 0; it < 8; ++it) {
                float4 a = Ar[it * 64 + lane], xv = xh[it * 64 + lane];
                acc.x = fmaf(a.x, xv.x, acc.x); acc.y = fmaf(a.y, xv.y, acc.y);
                acc.z = fmaf(a.z, xv.z, acc.z); acc.w = fmaf(a.w, xv.w, acc.w);
            }
            float d = acc.x + acc.y + acc.z + acc.w;
            #pragma unroll
            for (int off = 32; off; off >>= 1) d += __shfl_xor(d, off);
            if (lane == 0) tpart[wave] = d;
        }
        __syncthreads();
        if (tid < 8) {
            const int i = blk * 8 + tid;
            const float a  = tpart[2 * tid] + tpart[2 * tid + 1];
            const float bb = bvec[i];
            const float uu = uv[tid];
            float sn = a - bb + uu; sn = sn > 0.f ? sn : 0.f;
            const float un = uu + a - sn - bb;
            sv[tid] = sn; uv[tid] = un;
            astore(&rt[i], sn + bb - un);
        }
        fast_barrier(bstate, blk, bar_n); ++bar_n;
    }

    // ---- outputs: [x(4096), s(2048), u(2048), -u(2048)] ----
    if (tid < 16) out[blk * 16 + tid] = aload(&x0[blk * 16 + tid]);
    if (tid < 8) {
        const int i = blk * 8 + tid;
        out[4096 + i] = sv[tid];
        out[6144 + i] = uv[tid];
        out[8192 + i] = -uv[tid];
    }
}

extern "C" void kernel_launch(void* const* d_in, const int* in_sizes, int n_in,
                              void* d_out, int out_size, void* d_ws, size_t ws_size,
                              hipStream_t stream) {
    const float* A    = (const float*)d_in[0];   // 2048*4096
    const float* bvec = (const float*)d_in[1];   // 2048
    const float* cvec = (const float*)d_in[2];   // 4096
    float* out = (float*)d_out;

    float* ws = (float*)d_ws;
    float* x0 = ws;                    // 4096
    float* x1 = ws + 4096;             // 4096
    float* rt = ws + 8192;             // 2048
    unsigned* bstate = (unsigned*)(ws + 12288);  // 320 uints

    void* args[] = { (void*)&A, (void*)&bvec, (void*)&cvec, (void*)&out,
                     (void*)&x0, (void*)&x1, (void*)&rt, (void*)&bstate };
    hipError_t err = hipLaunchCooperativeKernel((const void*)admm_gram,
                               dim3(256), dim3(1024), args, 0, stream);
    (void)err;
}